// Round 1
// baseline (1867.858 us; speedup 1.0000x reference)
//
#include <hip/hip_runtime.h>
#include <stdint.h>

// Problem constants (LoRAGate): B=65536 tokens, D=4096, E=64 experts, K=8 top-k.
// Output layout: router_output [B,64] flat, then load_loss scalar at index B*64.

typedef __bf16 bf16x8 __attribute__((ext_vector_type(8)));
typedef float f32x4 __attribute__((ext_vector_type(4)));
typedef unsigned short ushort8 __attribute__((ext_vector_type(8)));
typedef float float4v __attribute__((ext_vector_type(4)));

__device__ __forceinline__ unsigned short f2bf(float f) {
    unsigned u = __builtin_bit_cast(unsigned, f);
    u += 0x7fffu + ((u >> 16) & 1u);   // round-to-nearest-even truncation
    return (unsigned short)(u >> 16);
}

__device__ __forceinline__ float wave_sum(float x) {
    #pragma unroll
    for (int off = 32; off; off >>= 1) x += __shfl_xor(x, off);
    return x;
}

// One block = 64 tokens. 4 waves; each wave computes M=64 x 32 output cols
// (2 n-tiles of the 128 total: [gate 0..63 | noise 0..63]).
__global__ __launch_bounds__(256, 4) void gate_kernel(
    const float* __restrict__ x, const float* __restrict__ wg,
    const float* __restrict__ wn, const float* __restrict__ noise,
    float* __restrict__ out, float* __restrict__ ws_part)
{
    __shared__ union {
        struct {
            unsigned short xs[64 * 32];    // x tile  [m][k] bf16, 4 KB
            unsigned short wsb[128 * 32];  // w tile  [n][k] bf16, 8 KB (transposed)
        } st;
        float logits[64 * 128];            // epilogue reuse, 32 KB
    } sm;
    __shared__ float red[8];

    const int t    = threadIdx.x;
    const int lane = t & 63;
    const int wv   = t >> 6;
    const int m0   = blockIdx.x * 64;

    const int q  = lane >> 4;   // k-quad for MFMA frags
    const int lm = lane & 15;

    f32x4 acc[4][2];
    #pragma unroll
    for (int mt = 0; mt < 4; ++mt)
        #pragma unroll
        for (int nt = 0; nt < 2; ++nt)
            acc[mt][nt] = (f32x4){0.f, 0.f, 0.f, 0.f};

    // staging roles
    const int sx_m = t >> 2;            // token row 0..63
    const int sx_k = (t & 3) * 8;       // k-octet within 32
    const int sw_n = t & 63;            // expert col
    const int sw_sel = (t >> 6) & 1;    // 0=gate 1=noise
    const int sw_kh = (t >> 7) & 1;     // k-half within 32
    const float* wptr = sw_sel ? wn : wg;

    for (int k0 = 0; k0 < 4096; k0 += 32) {
        __syncthreads();
        // ---- stage x tile: 64x32 fp32 -> bf16 LDS [m][k] ----
        const float* xg = x + (size_t)(m0 + sx_m) * 4096 + k0 + sx_k;
        float4v v0 = *(const float4v*)xg;
        float4v v1 = *(const float4v*)(xg + 4);
        ushort8 xb;
        xb[0] = f2bf(v0[0]); xb[1] = f2bf(v0[1]); xb[2] = f2bf(v0[2]); xb[3] = f2bf(v0[3]);
        xb[4] = f2bf(v1[0]); xb[5] = f2bf(v1[1]); xb[6] = f2bf(v1[2]); xb[7] = f2bf(v1[3]);
        *(ushort8*)&sm.st.xs[sx_m * 32 + sx_k] = xb;

        // ---- stage w tile: 32x64 fp32 (both mats) -> bf16 LDS [n][k] ----
        const float* wgp = wptr + (size_t)(k0 + sw_kh * 16) * 64 + sw_n;
        ushort8 wb0, wb1;
        #pragma unroll
        for (int i = 0; i < 8; ++i) wb0[i] = f2bf(wgp[i * 64]);
        #pragma unroll
        for (int i = 0; i < 8; ++i) wb1[i] = f2bf(wgp[(8 + i) * 64]);
        const int wrow = sw_sel * 64 + sw_n;
        *(ushort8*)&sm.st.wsb[wrow * 32 + sw_kh * 16]     = wb0;
        *(ushort8*)&sm.st.wsb[wrow * 32 + sw_kh * 16 + 8] = wb1;
        __syncthreads();

        // ---- MFMA: A[m=lm][k=q*8+j], B[n=lm][k=q*8+j] ----
        bf16x8 a[4], b[2];
        #pragma unroll
        for (int mt = 0; mt < 4; ++mt)
            a[mt] = *(const bf16x8*)&sm.st.xs[(mt * 16 + lm) * 32 + q * 8];
        #pragma unroll
        for (int nt = 0; nt < 2; ++nt)
            b[nt] = *(const bf16x8*)&sm.st.wsb[((wv * 2 + nt) * 16 + lm) * 32 + q * 8];
        #pragma unroll
        for (int mt = 0; mt < 4; ++mt)
            #pragma unroll
            for (int nt = 0; nt < 2; ++nt)
                acc[mt][nt] = __builtin_amdgcn_mfma_f32_16x16x32_bf16(
                    a[mt], b[nt], acc[mt][nt], 0, 0, 0);
    }

    __syncthreads();
    // ---- spill logits to LDS: C/D layout col=lm, row=q*4+r ----
    #pragma unroll
    for (int mt = 0; mt < 4; ++mt)
        #pragma unroll
        for (int nt = 0; nt < 2; ++nt)
            #pragma unroll
            for (int r = 0; r < 4; ++r)
                sm.logits[(mt * 16 + q * 4 + r) * 128 + (wv * 2 + nt) * 16 + lm] =
                    acc[mt][nt][r];
    __syncthreads();

    // ---- per-row epilogue: wave wv handles rows wv*16..wv*16+15, lane=expert ----
    float a1 = 0.f, a2 = 0.f;
    for (int rr = 0; rr < 16; ++rr) {
        const int m = wv * 16 + rr;
        const float g = sm.logits[m * 128 + lane];
        const float z = sm.logits[m * 128 + 64 + lane];
        const float sp = fmaxf(z, 0.f) + log1pf(__expf(-fabsf(z)));  // softplus
        const float lg = g + noise[(size_t)(m0 + m) * 64 + lane] * sp;

        // top-8 by iterative argmax extraction (lowest-index tie-break = lax.top_k)
        float v = lg;
        bool sel = false;
        float rowmax = 0.f;
        #pragma unroll
        for (int it = 0; it < 8; ++it) {
            float mv = v; int mi = lane;
            #pragma unroll
            for (int off = 32; off; off >>= 1) {
                float ov = __shfl_xor(mv, off);
                int   oi = __shfl_xor(mi, off);
                if (ov > mv || (ov == mv && oi < mi)) { mv = ov; mi = oi; }
            }
            if (it == 0) rowmax = mv;
            if (lane == mi) { sel = true; v = -__builtin_inff(); }
        }

        const float ef = __expf(lg - rowmax);
        const float es = sel ? ef : 0.f;
        const float ssum = wave_sum(es);
        const float fsum = wave_sum(ef);
        out[(size_t)(m0 + m) * 64 + lane] = es / ssum;   // sparse softmax
        const float pf = ef / fsum;                       // full softmax
        a1 += pf;
        a2 += pf * pf;
    }

    a1 = wave_sum(a1);
    a2 = wave_sum(a2);
    if (lane == 0) { red[wv * 2] = a1; red[wv * 2 + 1] = a2; }
    __syncthreads();
    if (t == 0) {
        ws_part[blockIdx.x * 2]     = red[0] + red[2] + red[4] + red[6];
        ws_part[blockIdx.x * 2 + 1] = red[1] + red[3] + red[5] + red[7];
    }
}

__global__ void finalize_kernel(const float* __restrict__ ws_part,
                                float* __restrict__ out)
{
    __shared__ double sred[8];
    const int t = threadIdx.x;
    const int lane = t & 63;
    const int wv = t >> 6;
    double l1 = 0.0, l2 = 0.0;
    for (int i = t; i < 1024; i += 256) {
        l1 += (double)ws_part[2 * i];
        l2 += (double)ws_part[2 * i + 1];
    }
    #pragma unroll
    for (int off = 32; off; off >>= 1) {
        l1 += __shfl_xor(l1, off);
        l2 += __shfl_xor(l2, off);
    }
    if (lane == 0) { sred[wv * 2] = l1; sred[wv * 2 + 1] = l2; }
    __syncthreads();
    if (t == 0) {
        const double s1 = sred[0] + sred[2] + sred[4] + sred[6];
        const double s2 = sred[1] + sred[3] + sred[5] + sred[7];
        const double N = 4194304.0;          // B*E
        const double mean = s1 / N;
        const double var = (s2 - s1 * s1 / N) / (N - 1.0);  // ddof=1
        const double loss = var / (mean * mean + 1e-10);
        out[4194304] = (float)loss;
    }
}

extern "C" void kernel_launch(void* const* d_in, const int* in_sizes, int n_in,
                              void* d_out, int out_size, void* d_ws, size_t ws_size,
                              hipStream_t stream) {
    const float* x     = (const float*)d_in[0];
    const float* wg    = (const float*)d_in[1];
    const float* wn    = (const float*)d_in[2];
    const float* noise = (const float*)d_in[3];
    float* out = (float*)d_out;
    float* ws  = (float*)d_ws;   // 1024 blocks x {sum_p, sum_p2} = 8 KB

    gate_kernel<<<dim3(1024), dim3(256), 0, stream>>>(x, wg, wn, noise, out, ws);
    finalize_kernel<<<dim3(1), dim3(256), 0, stream>>>(ws, out);
}

// Round 2
// 1550.296 us; speedup vs baseline: 1.2048x; 1.2048x over previous
//
#include <hip/hip_runtime.h>
#include <stdint.h>

// LoRAGate: B=65536 tokens, D=4096, E=64 experts, K=8 top-k.
// Output: router_output [B,64] flat, then load_loss scalar at index B*64.
//
// Round-2 design: NO LDS in the GEMM K-loop.
//   - A (x) fragments loaded straight from global: lane(q,lm) reads
//     x[row=wv*16+lm][k0+q*8 .. +8] (two dwordx4), converted fp32->bf16 in regs.
//   - B (w) fragments pre-laid-out by prep_w into d_ws in exact MFMA
//     B-operand order: wB[(s*8+nt)*512 + lane*8 + j] bf16  (1 MB, L2-resident),
//     so each frag is ONE coalesced global_load_dwordx4.
//   - No __syncthreads in the K-loop; 16 waves/CU hide latency.
// LDS used only for the one-shot logits epilogue (top-k + softmax).

typedef __bf16 bf16x8 __attribute__((ext_vector_type(8)));
typedef float f32x4 __attribute__((ext_vector_type(4)));
typedef unsigned short ushort8 __attribute__((ext_vector_type(8)));

__device__ __forceinline__ unsigned short f2bf(float f) {
    unsigned u = __builtin_bit_cast(unsigned, f);
    u += 0x7fffu + ((u >> 16) & 1u);   // RTNE truncation
    return (unsigned short)(u >> 16);
}

__device__ __forceinline__ float wave_sum(float x) {
    #pragma unroll
    for (int off = 32; off; off >>= 1) x += __shfl_xor(x, off);
    return x;
}

// Build bf16 B-fragment layout: value(s, nt, lane=q*16+lm, j) =
//   w_col[k = s*32 + q*8 + j][n = (nt&3)*16 + lm],  nt<4 -> w_gate, nt>=4 -> w_noise.
__global__ void prep_w(const float* __restrict__ wg, const float* __restrict__ wn,
                       unsigned short* __restrict__ wB)
{
    const int s = blockIdx.x;                 // kstep 0..127
    for (int slot = threadIdx.x; slot < 512; slot += 256) {
        const int nt = slot >> 6;             // 0..7
        const int lane = slot & 63;
        const int q = lane >> 4, lm = lane & 15;
        const float* src = (nt < 4) ? wg : wn;
        const int n = (nt & 3) * 16 + lm;
        const int kbase = s * 32 + q * 8;
        ushort8 v;
        #pragma unroll
        for (int j = 0; j < 8; ++j)
            v[j] = f2bf(src[(size_t)(kbase + j) * 64 + n]);
        *(ushort8*)&wB[((size_t)(s * 8 + nt) * 64 + lane) * 8] = v;
    }
}

__global__ __launch_bounds__(256, 4) void gate_kernel(
    const float* __restrict__ x, const unsigned short* __restrict__ wB,
    const float* __restrict__ noise, float* __restrict__ out,
    float* __restrict__ ws_part)
{
    __shared__ float logits[64 * 128];   // 32 KB, epilogue only
    __shared__ float red[8];

    const int t = threadIdx.x;
    const int lane = t & 63;
    const int wv = t >> 6;
    const int q = lane >> 4, lm = lane & 15;
    const int m0 = blockIdx.x * 64;

    // A stream: this lane's row, k chunk q*8 of each 32-wide k-step
    const float* xp = x + (size_t)(m0 + wv * 16 + lm) * 4096 + q * 8;
    const unsigned short* wp = wB + (size_t)lane * 8;

    f32x4 acc[8];
    #pragma unroll
    for (int nt = 0; nt < 8; ++nt) acc[nt] = (f32x4){0.f, 0.f, 0.f, 0.f};

    #pragma unroll 2
    for (int s = 0; s < 128; ++s) {
        f32x4 a0 = *(const f32x4*)xp;
        f32x4 a1 = *(const f32x4*)(xp + 4);
        xp += 32;
        const unsigned short* w_s = wp + (size_t)s * 4096;  // (s*8+nt)*512 + lane*8
        ushort8 ab;
        ab[0] = f2bf(a0[0]); ab[1] = f2bf(a0[1]);
        ab[2] = f2bf(a0[2]); ab[3] = f2bf(a0[3]);
        ab[4] = f2bf(a1[0]); ab[5] = f2bf(a1[1]);
        ab[6] = f2bf(a1[2]); ab[7] = f2bf(a1[3]);
        bf16x8 af = __builtin_bit_cast(bf16x8, ab);
        #pragma unroll
        for (int nt = 0; nt < 8; ++nt) {
            bf16x8 bfr = *(const bf16x8*)(w_s + nt * 512);
            acc[nt] = __builtin_amdgcn_mfma_f32_16x16x32_bf16(af, bfr, acc[nt], 0, 0, 0);
        }
    }

    // ---- dump logits: C/D layout col=lm, row=q*4+r; wave wv owns rows wv*16.. ----
    #pragma unroll
    for (int nt = 0; nt < 8; ++nt)
        #pragma unroll
        for (int r = 0; r < 4; ++r)
            logits[(wv * 16 + q * 4 + r) * 128 + nt * 16 + lm] = acc[nt][r];
    __syncthreads();

    // ---- per-row epilogue: wave wv handles rows wv*16..+15, lane=expert ----
    float p1 = 0.f, p2 = 0.f;
    for (int rr = 0; rr < 16; ++rr) {
        const int m = wv * 16 + rr;
        const float g = logits[m * 128 + lane];
        const float z = logits[m * 128 + 64 + lane];
        const float sp = fmaxf(z, 0.f) + log1pf(__expf(-fabsf(z)));  // softplus
        const float lg = g + noise[(size_t)(m0 + m) * 64 + lane] * sp;

        // top-8 via iterative argmax (lowest-index tie-break = lax.top_k)
        float v = lg;
        bool sel = false;
        float rowmax = 0.f;
        #pragma unroll
        for (int it = 0; it < 8; ++it) {
            float mv = v; int mi = lane;
            #pragma unroll
            for (int off = 32; off; off >>= 1) {
                float ov = __shfl_xor(mv, off);
                int   oi = __shfl_xor(mi, off);
                if (ov > mv || (ov == mv && oi < mi)) { mv = ov; mi = oi; }
            }
            if (it == 0) rowmax = mv;
            if (lane == mi) { sel = true; v = -__builtin_inff(); }
        }

        const float ef = __expf(lg - rowmax);
        const float es = sel ? ef : 0.f;
        const float ssum = wave_sum(es);
        const float fsum = wave_sum(ef);
        out[(size_t)(m0 + m) * 64 + lane] = es / ssum;   // sparse softmax
        const float pf = ef / fsum;                       // full softmax
        p1 += pf;
        p2 += pf * pf;
    }

    p1 = wave_sum(p1);
    p2 = wave_sum(p2);
    if (lane == 0) { red[wv * 2] = p1; red[wv * 2 + 1] = p2; }
    __syncthreads();
    if (t == 0) {
        ws_part[blockIdx.x * 2]     = red[0] + red[2] + red[4] + red[6];
        ws_part[blockIdx.x * 2 + 1] = red[1] + red[3] + red[5] + red[7];
    }
}

__global__ void finalize_kernel(const float* __restrict__ ws_part,
                                float* __restrict__ out)
{
    __shared__ double sred[8];
    const int t = threadIdx.x;
    const int lane = t & 63;
    const int wv = t >> 6;
    double l1 = 0.0, l2 = 0.0;
    for (int i = t; i < 1024; i += 256) {
        l1 += (double)ws_part[2 * i];
        l2 += (double)ws_part[2 * i + 1];
    }
    #pragma unroll
    for (int off = 32; off; off >>= 1) {
        l1 += __shfl_xor(l1, off);
        l2 += __shfl_xor(l2, off);
    }
    if (lane == 0) { sred[wv * 2] = l1; sred[wv * 2 + 1] = l2; }
    __syncthreads();
    if (t == 0) {
        const double s1 = sred[0] + sred[2] + sred[4] + sred[6];
        const double s2 = sred[1] + sred[3] + sred[5] + sred[7];
        const double N = 4194304.0;          // B*E
        const double mean = s1 / N;
        const double var = (s2 - s1 * s1 / N) / (N - 1.0);  // ddof=1
        const double loss = var / (mean * mean + 1e-10);
        out[4194304] = (float)loss;
    }
}

extern "C" void kernel_launch(void* const* d_in, const int* in_sizes, int n_in,
                              void* d_out, int out_size, void* d_ws, size_t ws_size,
                              hipStream_t stream) {
    const float* x     = (const float*)d_in[0];
    const float* wg    = (const float*)d_in[1];
    const float* wn    = (const float*)d_in[2];
    const float* noise = (const float*)d_in[3];
    float* out = (float*)d_out;
    float* ws  = (float*)d_ws;                                  // [0,8KB): partials
    unsigned short* wB = (unsigned short*)((char*)d_ws + 8192); // [8KB, 8KB+1MB): B frags

    prep_w<<<dim3(128), dim3(256), 0, stream>>>(wg, wn, wB);
    gate_kernel<<<dim3(1024), dim3(256), 0, stream>>>(x, wB, noise, out, ws);
    finalize_kernel<<<dim3(1), dim3(256), 0, stream>>>(ws, out);
}